// Round 8
// baseline (1904.760 us; speedup 1.0000x reference)
//
#include <hip/hip_runtime.h>

#define B_   32
#define T_   300
#define C1_  2312
#define O1_  512
#define O2_  512
#define O3_  10
#define M_   (B_*T_)   // 9600
#define KSPLIT_ 1152   // gemm1 K halves: [0,1152) = 72 tiles, [1152,2312) = 73 tiles

// ---------------- weight prep (all f64) ----------------

__global__ void calc_f(const float* __restrict__ v, const float* __restrict__ g,
                       double* __restrict__ f, int O, int C) {
    int o = blockIdx.x;
    const float* row = v + (size_t)o * C;
    double s = 0.0;
    for (int c = threadIdx.x; c < C; c += blockDim.x) {
        double x = (double)row[c];
        s += x * x;
    }
    for (int off = 32; off; off >>= 1) s += __shfl_down(s, off);
    __shared__ double wsum[4];
    int lane = threadIdx.x & 63, wv = threadIdx.x >> 6;
    if (lane == 0) wsum[wv] = s;
    __syncthreads();
    if (threadIdx.x == 0) {
        double tot = 0.0;
        for (int i = 0; i < (int)(blockDim.x >> 6); ++i) tot += wsum[i];
        f[o] = (double)g[o] / sqrt(tot);
    }
}

// wt[c*ldo + o] = v[o*C + c] * f[o]   (double)
__global__ void transpose_scale(const float* __restrict__ v, const double* __restrict__ f,
                                double* __restrict__ wt, int O, int C, int ldo) {
    __shared__ double tile[32][33];
    int c0 = blockIdx.x * 32, o0 = blockIdx.y * 32;
    int tx = threadIdx.x, ty = threadIdx.y;
    for (int k = 0; k < 4; ++k) {
        int o = o0 + ty + k * 8, c = c0 + tx;
        double val = 0.0;
        if (o < O && c < C) val = (double)v[(size_t)o * C + c] * f[o];
        tile[ty + k * 8][tx] = val;
    }
    __syncthreads();
    for (int k = 0; k < 4; ++k) {
        int c = c0 + ty + k * 8, o = o0 + tx;
        if (c < C && o < O) wt[(size_t)c * ldo + o] = tile[tx][ty + k * 8];
    }
}

// ---------------- spike -> bitmask precompute ----------------
__global__ void build_bits(const float* __restrict__ X, unsigned* __restrict__ bits) {
    size_t idx = (size_t)blockIdx.x * 256 + threadIdx.x;
    if (idx >= (size_t)B_ * C1_ * 10) return;
    int t32 = (int)(idx % 10);
    size_t bc = idx / 10;
    const float* src = X + bc * T_ + t32 * 32;
    int nq = (t32 == 9) ? 3 : 8;   // 12 or 32 valid t's (T_=300)
    unsigned m = 0;
    for (int q = 0; q < nq; ++q) {
        float4 v = *(const float4*)(src + q * 4);
        if (v.x != 0.f) m |= 1u << (q * 4 + 0);
        if (v.y != 0.f) m |= 1u << (q * 4 + 1);
        if (v.z != 0.f) m |= 1u << (q * 4 + 2);
        if (v.w != 0.f) m |= 1u << (q * 4 + 3);
    }
    bits[idx] = m;
}

// ---------------- GEMM layer 1 v8 (round-4 skeleton, 32t x 64o wave geometry) ----------------
// r5-r7 verdict: LDS staging + 1-barrier dbuf is the right skeleton (320 us);
// L2-direct variants lose on latency/issue pressure.  v8 keeps the skeleton
// and changes only the wave->(t,o) mapping: a wave owns 32 t x 64 o (was
// 8 t x 256 o).  Per c-hit: ONE ds_read_b64 (8 B/lane) serves 32 t's, vs
// 4 reads serving 8 t's -> LDS-read instrs and bytes both -58% at identical
// useful-add count.  Mask gate = full 32-bit word (1 readlane, no shifts).
// Block: 512 thr = 8 waves = 2 t-halves x 4 o-quarters covering 64t x 256o.
// K=2 plain partial stores (Z0/Z1), scan12 combines in fixed order ->
// bit-identical to round 4 (absmax 0.0).
__global__ __launch_bounds__(512, 4) void gemm1(const unsigned* __restrict__ Xbits,
                                                const double* __restrict__ Wt,
                                                double* __restrict__ Z0,
                                                double* __restrict__ Z1) {
    __shared__ double Ws[2][16][256];   // 64 KB double-buffer
    int n = blockIdx.x;
    int combo = n & 3;                  // (khalf, ohalf); n&7 -> XCD pins one W slice
    int khalf = combo & 1;
    int o0 = (combo >> 1) * 256;
    int i = n >> 2;                     // 0..159
    int twin = i % 5;                   // 64-t window
    int b = i / 5;                      // 0..31
    int tid = threadIdx.x;
    int w = tid >> 6;                   // 0..7
    int lane = tid & 63;
    int th = w >> 2;                    // t-half (32 t) of the 64-t window
    int oq = w & 3;                     // o-quarter (64 o) of the 256-o block
    int word = twin * 2 + th;           // 32-bit mask word index 0..9
    int cbeg = khalf ? KSPLIT_ : 0;
    int qend = khalf ? C1_ : KSPLIT_;
    const int NT = khalf ? 73 : 72;
    double* __restrict__ Z = khalf ? Z1 : Z0;
    double acc[32];
#pragma unroll
    for (int tj = 0; tj < 32; ++tj) acc[tj] = 0.0;
    const unsigned* xbp = Xbits + (size_t)b * C1_ * 10 + word;

    double2 wreg[4];
    unsigned mval, mvaln = 0u;

    auto load_w = [&](int c0) {
#pragma unroll
        for (int h = 0; h < 4; ++h) {
            int idx = h * 512 + tid;
            int r = idx >> 7, od = (idx & 127) * 2;
            int c = c0 + r;
            double2 val; val.x = 0.0; val.y = 0.0;
            if (c < qend) val = *(const double2*)(Wt + (size_t)c * O1_ + o0 + od);
            wreg[h] = val;
        }
    };
    auto load_m = [&](int c0) -> unsigned {
        int c = c0 + lane;
        return (lane < 16 && c < qend) ? xbp[(size_t)c * 10] : 0u;
    };
    auto store_w = [&](int bi) {
#pragma unroll
        for (int h = 0; h < 4; ++h) {
            int idx = h * 512 + tid;
            int r = idx >> 7, od = (idx & 127) * 2;
            *(double2*)(&Ws[bi][r][od]) = wreg[h];
        }
    };

    load_w(cbeg);
    mval = load_m(cbeg);
    store_w(0);
    __syncthreads();
    int cur = 0;
    for (int tile = 0; tile < NT; ++tile) {
        if (tile + 1 < NT) {
            int cn = cbeg + (tile + 1) * 16;
            load_w(cn);            // prefetch next tile into regs (covered by compute)
            mvaln = load_m(cn);
        }
#pragma unroll
        for (int k = 0; k < 16; ++k) {
            unsigned m32 = (unsigned)__builtin_amdgcn_readlane((int)mval, k);
            if (m32) {             // wave-uniform scalar branch
                double wf = Ws[cur][k][oq * 64 + lane];   // ONE b64 read serves 32 t
#pragma unroll
                for (int nb = 0; nb < 4; ++nb) {
                    if (m32 & (0xffu << (nb * 8))) {      // byte-level skip
#pragma unroll
                        for (int e = 0; e < 8; ++e) {
                            int tj = nb * 8 + e;
                            if (m32 & (1u << tj)) acc[tj] += wf;
                        }
                    }
                }
            }
        }
        if (tile + 1 < NT) {
            store_w(cur ^ 1);      // other buffer: its readers finished before last barrier
            __syncthreads();       // ONE barrier per tile
        }
        mval = mvaln;
        cur ^= 1;
    }
#pragma unroll
    for (int tj = 0; tj < 32; ++tj) {
        int t = twin * 64 + th * 32 + tj;
        if (t < T_) {
            Z[((size_t)b * T_ + t) * O1_ + o0 + oq * 64 + lane] = acc[tj];   // plain K-partial
        }
    }
}

// ---------------- GEMM layer 2 sparse v8 (same skeleton + 32t x 64o geometry) ----------------
// Sbits: [B, 512, 10] u32 (delayed s1 spikes) ; Wt: [512, 512] f64.
// s1 density is high, so the old octet gate rarely skipped; the win here is
// 1 b64 read per (k, 64o) serving 32 t -> ~3.4x fewer LDS bytes.
// K=2 halves (c 0..256 / 256..512), plain partial stores, fixed-order combine.
__global__ __launch_bounds__(512, 4) void gemm2s(const unsigned* __restrict__ Sbits,
                                                 const double* __restrict__ Wt,
                                                 double* __restrict__ Z0,
                                                 double* __restrict__ Z1) {
    __shared__ double Ws[2][16][256];   // 64 KB
    int n = blockIdx.x;
    int combo = n & 3;
    int khalf = combo & 1;
    int o0 = (combo >> 1) * 256;
    int i = n >> 2;                  // 0..159
    int twin = i % 5;                // 64-t window
    int b = i / 5;
    int tid = threadIdx.x;
    int w = tid >> 6;                // 0..7
    int lane = tid & 63;
    int th = w >> 2;                 // t-half
    int oq = w & 3;                  // o-quarter
    int word = twin * 2 + th;
    int cbeg = khalf * 256;
    double* __restrict__ Z = khalf ? Z1 : Z0;
    double acc[32];
#pragma unroll
    for (int tj = 0; tj < 32; ++tj) acc[tj] = 0.0;
    const unsigned* xbp = Sbits + (size_t)b * O1_ * 10 + word;

    double2 wreg[4];
    unsigned mval, mvaln = 0u;

    auto load_w = [&](int c0) {
#pragma unroll
        for (int h = 0; h < 4; ++h) {
            int idx = h * 512 + tid;
            int r = idx >> 7, od = (idx & 127) * 2;
            int c = c0 + r;
            wreg[h] = *(const double2*)(Wt + (size_t)c * O2_ + o0 + od);
        }
    };
    auto load_m = [&](int c0) -> unsigned {
        int c = c0 + lane;
        return (lane < 16) ? xbp[(size_t)c * 10] : 0u;
    };
    auto store_w = [&](int bi) {
#pragma unroll
        for (int h = 0; h < 4; ++h) {
            int idx = h * 512 + tid;
            int r = idx >> 7, od = (idx & 127) * 2;
            *(double2*)(&Ws[bi][r][od]) = wreg[h];
        }
    };

    load_w(cbeg);
    mval = load_m(cbeg);
    store_w(0);
    __syncthreads();
    int cur = 0;
    for (int tile = 0; tile < 16; ++tile) {
        if (tile + 1 < 16) {
            int cn = cbeg + (tile + 1) * 16;
            load_w(cn);
            mvaln = load_m(cn);
        }
#pragma unroll
        for (int k = 0; k < 16; ++k) {
            unsigned m32 = (unsigned)__builtin_amdgcn_readlane((int)mval, k);
            if (m32) {
                double wf = Ws[cur][k][oq * 64 + lane];
#pragma unroll
                for (int nb = 0; nb < 4; ++nb) {
                    if (m32 & (0xffu << (nb * 8))) {
#pragma unroll
                        for (int e = 0; e < 8; ++e) {
                            int tj = nb * 8 + e;
                            if (m32 & (1u << tj)) acc[tj] += wf;
                        }
                    }
                }
            }
        }
        if (tile + 1 < 16) {
            store_w(cur ^ 1);
            __syncthreads();
        }
        mval = mvaln;
        cur ^= 1;
    }
#pragma unroll
    for (int tj = 0; tj < 32; ++tj) {
        int t = twin * 64 + th * 32 + tj;
        if (t < T_) {
            Z[((size_t)b * T_ + t) * O2_ + o0 + oq * 64 + lane] = acc[tj];
        }
    }
}

// ---------------- GEMM layer 3 (f64 acc) ----------------
__global__ void gemm3(const float* __restrict__ A,
                      const double* __restrict__ Wt,
                      double* __restrict__ Z) {
    __shared__ double w[512 * 16];
    for (int e = threadIdx.x; e < 4096; e += 256)
        ((double2*)w)[e] = ((const double2*)Wt)[e];
    __syncthreads();
    int m = blockIdx.x * 256 + threadIdx.x;
    if (m >= M_) return;
    double acc[O3_];
#pragma unroll
    for (int o = 0; o < O3_; ++o) acc[o] = 0.0;
    const float4* Ar = (const float4*)(A + (size_t)m * 512);
    for (int cq = 0; cq < 128; ++cq) {
        float4 a = Ar[cq];
        float av[4] = {a.x, a.y, a.z, a.w};
#pragma unroll
        for (int u = 0; u < 4; ++u)
#pragma unroll
            for (int o = 0; o < O3_; ++o) acc[o] += (double)av[u] * w[(cq * 4 + u) * 16 + o];
    }
    double* dst = Z + (size_t)m * 16;
#pragma unroll
    for (int o = 0; o < O3_; ++o) dst[o] = acc[o];
}

// ---------------- LIF scan + delay, layers 1/2 (O=512, f64 state) ----------------
__global__ void scan12(const double* __restrict__ Za,   // [B, T, 512] f64
                       const double* __restrict__ Zb,   // partial 2 or nullptr
                       const int* __restrict__ delay,   // [512]
                       float* __restrict__ Sout,        // [B, T, 512] f32 or nullptr
                       unsigned* __restrict__ bitsOut,  // [B, 512, 10] u32 or nullptr
                       float* __restrict__ sumOut) {
    int blk = blockIdx.x;
    int o = (blk & 7) * 64 + threadIdx.x;
    int b = blk >> 3;
    size_t base = (size_t)b * T_ * O1_ + o;
    const double* z  = Za + base;
    const double* z2 = Zb ? Zb + base : nullptr;
    float* s = Sout ? Sout + base : nullptr;
    int d = delay[o];
    if (s) for (int t = 0; t < d; ++t) s[(size_t)t * O1_] = 0.f;
    double cur = 0.0, vol = 0.0;
    float cnt = 0.f;
    unsigned bw = 0u;   // running bit word; d<32 so words 0..8 flush in-loop
    for (int t8 = 0; t8 < 296; t8 += 8) {
        double zbuf[8];
#pragma unroll
        for (int u = 0; u < 8; ++u) zbuf[u] = z[(size_t)(t8 + u) * O1_];
        if (z2) {
#pragma unroll
            for (int u = 0; u < 8; ++u) zbuf[u] += z2[(size_t)(t8 + u) * O1_];
        }
#pragma unroll
        for (int u = 0; u < 8; ++u) {
            int t = t8 + u;
            cur = cur * 0.75 + zbuf[u];
            vol = vol * 0.97 + cur;
            float sp = (vol >= 1.25) ? 1.f : 0.f;
            if (sp > 0.f) vol = 0.0;
            int tw = t + d;
            if (tw < T_) {
                if (s) s[(size_t)tw * O1_] = sp;
                cnt += sp;
                if (bitsOut) {
                    if (sp > 0.f) bw |= 1u << (tw & 31);
                    if ((tw & 31) == 31) { bitsOut[((size_t)b * O1_ + o) * 10 + (tw >> 5)] = bw; bw = 0u; }
                }
            }
        }
    }
    {
        double zbuf[4];
#pragma unroll
        for (int u = 0; u < 4; ++u) zbuf[u] = z[(size_t)(296 + u) * O1_];
        if (z2) {
#pragma unroll
            for (int u = 0; u < 4; ++u) zbuf[u] += z2[(size_t)(296 + u) * O1_];
        }
#pragma unroll
        for (int u = 0; u < 4; ++u) {
            int t = 296 + u;
            cur = cur * 0.75 + zbuf[u];
            vol = vol * 0.97 + cur;
            float sp = (vol >= 1.25) ? 1.f : 0.f;
            if (sp > 0.f) vol = 0.0;
            int tw = t + d;
            if (tw < T_) {
                if (s) s[(size_t)tw * O1_] = sp;
                cnt += sp;
                if (bitsOut) {
                    if (sp > 0.f) bw |= 1u << (tw & 31);
                    if ((tw & 31) == 31) { bitsOut[((size_t)b * O1_ + o) * 10 + (tw >> 5)] = bw; bw = 0u; }
                }
            }
        }
    }
    if (bitsOut) bitsOut[((size_t)b * O1_ + o) * 10 + 9] = bw;  // word 9 never flushes in-loop
    for (int off = 32; off; off >>= 1) cnt += __shfl_down(cnt, off);
    if (threadIdx.x == 0) atomicAdd(sumOut, cnt);
}

// ---------------- LIF scan + delay, layer 3 (O=10, f64 state) ----------------
__global__ void scan3(const double* __restrict__ Z3,  // [M, 16] f64
                      const int* __restrict__ d3,     // [10]
                      float* __restrict__ out,        // d_out: [B, 10, 300] f32
                      float* __restrict__ sumOut) {
    __shared__ double zt[T_ * 16];
    int b = blockIdx.x;
    const double2* src = (const double2*)(Z3 + (size_t)b * T_ * 16);
    for (int e = threadIdx.x; e < T_ * 8; e += 64)
        ((double2*)zt)[e] = src[e];
    __syncthreads();
    int o = threadIdx.x;
    if (o < O3_) {
        int d = d3[o];
        float* dst = out + (size_t)b * O3_ * T_ + (size_t)o * T_;
        for (int t = 0; t < d; ++t) dst[t] = 0.f;
        double cur = 0.0, vol = 0.0;
        float cnt = 0.f;
        for (int t = 0; t < T_; ++t) {
            cur = cur * 0.75 + zt[t * 16 + o];
            vol = vol * 0.97 + cur;
            float sp = (vol >= 1.25) ? 1.f : 0.f;
            if (sp > 0.f) vol = 0.0;
            int tw = t + d;
            if (tw < T_) { dst[tw] = sp; cnt += sp; }
        }
        atomicAdd(sumOut, cnt);
    }
}

__global__ void finalize(const float* __restrict__ sums, float* __restrict__ out) {
    if (threadIdx.x == 0) {
        out[0] = (float)((double)sums[0] / (double)(B_ * O1_ * T_));
        out[1] = (float)((double)sums[1] / (double)(B_ * O2_ * T_));
        out[2] = (float)((double)sums[2] / (double)(B_ * O3_ * T_));
    }
}

extern "C" void kernel_launch(void* const* d_in, const int* in_sizes, int n_in,
                              void* d_out, int out_size, void* d_ws, size_t ws_size,
                              hipStream_t stream) {
    const float* spike = (const float*)d_in[0];
    const float* v1 = (const float*)d_in[1];
    const float* g1 = (const float*)d_in[2];
    const float* v2 = (const float*)d_in[3];
    const float* g2 = (const float*)d_in[4];
    const float* v3 = (const float*)d_in[5];
    const float* g3 = (const float*)d_in[6];
    const int* d1 = (const int*)d_in[7];
    const int* d2 = (const int*)d_in[8];
    const int* d3 = (const int*)d_in[9];
    float* out = (float*)d_out;

    // Workspace: ~115 MB (round-4 layout).
    double* dw = (double*)d_ws;
    size_t off = 0;
    double* f1  = dw + off; off += 512;
    double* f2  = dw + off; off += 512;
    double* f3  = dw + off; off += 16;
    double* Wt1 = dw + off; off += (size_t)C1_ * O1_;
    double* Wt2 = dw + off; off += 512 * 512;
    double* Wt3 = dw + off; off += 512 * 16;
    double* zA  = dw + off; off += (size_t)M_ * 512;
    double* zB  = dw + off; off += (size_t)M_ * 512;
    double* z3b = dw + off; off += (size_t)M_ * 16;
    float* fw = (float*)(dw + off);
    float* sB    = fw;                                   // f32 spikes, M*512
    float* sums  = fw + (size_t)M_ * 512;                // 4 floats
    unsigned* Xbits = (unsigned*)(fw + (size_t)M_ * 512 + 4);  // B*C1*10 u32
    unsigned* bits2 = Xbits + (size_t)B_ * C1_ * 10;           // B*512*10 u32
    (void)ws_size; (void)out_size; (void)in_sizes; (void)n_in;

    hipMemsetAsync(sums, 0, 4 * sizeof(float), stream);

    build_bits<<<(B_ * C1_ * 10 + 255) / 256, 256, 0, stream>>>(spike, Xbits);

    calc_f<<<512, 256, 0, stream>>>(v1, g1, f1, O1_, C1_);
    calc_f<<<512, 256, 0, stream>>>(v2, g2, f2, O2_, O1_);
    calc_f<<<O3_, 256, 0, stream>>>(v3, g3, f3, O3_, O2_);

    transpose_scale<<<dim3((C1_ + 31) / 32, 16), dim3(32, 8), 0, stream>>>(v1, f1, Wt1, O1_, C1_, O1_);
    transpose_scale<<<dim3(16, 16), dim3(32, 8), 0, stream>>>(v2, f2, Wt2, O2_, O1_, O2_);
    transpose_scale<<<dim3(16, 1), dim3(32, 8), 0, stream>>>(v3, f3, Wt3, O3_, O2_, 16);

    // gemm1 v8: 640 blocks x 512 thr, dbuf 1-barrier, 32t x 64o waves, K=2 partials
    gemm1<<<640, 512, 0, stream>>>(Xbits, Wt1, zA, zB);
    // scan12 #1: sum zA+zB, emit ONLY bits (s1 floats are dead)
    scan12<<<256, 64, 0, stream>>>(zA, zB, d1, nullptr, bits2, sums + 0);
    // gemm2s v8: 640 blocks x 512 thr, same geometry, K=2 partials
    gemm2s<<<640, 512, 0, stream>>>(bits2, Wt2, zA, zB);
    // scan12 #2: sum zA+zB, emit ONLY floats (bits are dead)
    scan12<<<256, 64, 0, stream>>>(zA, zB, d2, sB, nullptr, sums + 1);
    gemm3<<<(M_ + 255) / 256, 256, 0, stream>>>(sB, Wt3, z3b);        // z3b = z3
    scan3<<<B_, 64, 0, stream>>>(z3b, d3, out, sums + 2);
    finalize<<<1, 64, 0, stream>>>(sums, out + (size_t)B_ * O3_ * T_);
}

// Round 9
// 794.915 us; speedup vs baseline: 2.3962x; 2.3962x over previous
//
#include <hip/hip_runtime.h>

#define B_   32
#define T_   300
#define C1_  2312
#define O1_  512
#define O2_  512
#define O3_  10
#define M_   (B_*T_)   // 9600
#define KSPLIT_ 1152   // gemm1 K halves: [0,1152) = 72 tiles, [1152,2312) = 73 tiles

// ---------------- weight prep (all f64) ----------------

__global__ void calc_f(const float* __restrict__ v, const float* __restrict__ g,
                       double* __restrict__ f, int O, int C) {
    int o = blockIdx.x;
    const float* row = v + (size_t)o * C;
    double s = 0.0;
    for (int c = threadIdx.x; c < C; c += blockDim.x) {
        double x = (double)row[c];
        s += x * x;
    }
    for (int off = 32; off; off >>= 1) s += __shfl_down(s, off);
    __shared__ double wsum[4];
    int lane = threadIdx.x & 63, wv = threadIdx.x >> 6;
    if (lane == 0) wsum[wv] = s;
    __syncthreads();
    if (threadIdx.x == 0) {
        double tot = 0.0;
        for (int i = 0; i < (int)(blockDim.x >> 6); ++i) tot += wsum[i];
        f[o] = (double)g[o] / sqrt(tot);
    }
}

// wt[c*ldo + o] = v[o*C + c] * f[o]   (double)
__global__ void transpose_scale(const float* __restrict__ v, const double* __restrict__ f,
                                double* __restrict__ wt, int O, int C, int ldo) {
    __shared__ double tile[32][33];
    int c0 = blockIdx.x * 32, o0 = blockIdx.y * 32;
    int tx = threadIdx.x, ty = threadIdx.y;
    for (int k = 0; k < 4; ++k) {
        int o = o0 + ty + k * 8, c = c0 + tx;
        double val = 0.0;
        if (o < O && c < C) val = (double)v[(size_t)o * C + c] * f[o];
        tile[ty + k * 8][tx] = val;
    }
    __syncthreads();
    for (int k = 0; k < 4; ++k) {
        int c = c0 + ty + k * 8, o = o0 + tx;
        if (c < C && o < O) wt[(size_t)c * ldo + o] = tile[tx][ty + k * 8];
    }
}

// ---------------- spike -> bitmask precompute ----------------
__global__ void build_bits(const float* __restrict__ X, unsigned* __restrict__ bits) {
    size_t idx = (size_t)blockIdx.x * 256 + threadIdx.x;
    if (idx >= (size_t)B_ * C1_ * 10) return;
    int t32 = (int)(idx % 10);
    size_t bc = idx / 10;
    const float* src = X + bc * T_ + t32 * 32;
    int nq = (t32 == 9) ? 3 : 8;   // 12 or 32 valid t's (T_=300)
    unsigned m = 0;
    for (int q = 0; q < nq; ++q) {
        float4 v = *(const float4*)(src + q * 4);
        if (v.x != 0.f) m |= 1u << (q * 4 + 0);
        if (v.y != 0.f) m |= 1u << (q * 4 + 1);
        if (v.z != 0.f) m |= 1u << (q * 4 + 2);
        if (v.w != 0.f) m |= 1u << (q * 4 + 3);
    }
    bits[idx] = m;
}

// ---------------- GEMM layer 1 (EXACT round-4 version: dbuf 1-barrier, K=2 partials) ----------------
// Measured 320 us, absmax 0.0.  X density 10% -> octet gates skip 43% and
// 4-adds-per-branch is the proven branch granularity (r8's 1-add-per-branch
// geometry got if-converted and ran 4x slower).  Do not touch.
__global__ __launch_bounds__(512, 4) void gemm1(const unsigned* __restrict__ Xbits,
                                                const double* __restrict__ Wt,
                                                double* __restrict__ Z0,
                                                double* __restrict__ Z1) {
    __shared__ double Ws[2][16][256];   // 64 KB double-buffer
    int n = blockIdx.x;
    int combo = n & 3;
    int khalf = combo & 1;
    int o0 = (combo >> 1) * 256;
    int i = n >> 2;                      // 0..159
    int tb = i % 10;                     // 32-t window
    int bpair = i / 10;                  // 0..15
    int tid = threadIdx.x;
    int w = tid >> 6;                    // 0..7
    int lane = tid & 63;
    int b = bpair * 2 + (w >> 2);
    int w8s = __builtin_amdgcn_readfirstlane((w & 3) << 3);  // octet bit shift
    int cbeg = khalf ? KSPLIT_ : 0;
    int qend = khalf ? C1_ : KSPLIT_;
    const int NT = khalf ? 73 : 72;
    double* __restrict__ Z = khalf ? Z1 : Z0;
    double acc[8][4];
#pragma unroll
    for (int tj = 0; tj < 8; ++tj)
#pragma unroll
        for (int i2 = 0; i2 < 4; ++i2) acc[tj][i2] = 0.0;
    const unsigned* xbp = Xbits + (size_t)b * C1_ * 10 + tb;

    double2 wreg[4];
    unsigned mval, mvaln = 0u;

    auto load_w = [&](int c0) {
#pragma unroll
        for (int h = 0; h < 4; ++h) {
            int idx = h * 512 + tid;
            int r = idx >> 7, od = (idx & 127) * 2;
            int c = c0 + r;
            double2 val; val.x = 0.0; val.y = 0.0;
            if (c < qend) val = *(const double2*)(Wt + (size_t)c * O1_ + o0 + od);
            wreg[h] = val;
        }
    };
    auto load_m = [&](int c0) -> unsigned {
        int c = c0 + lane;
        return (lane < 16 && c < qend) ? xbp[(size_t)c * 10] : 0u;
    };
    auto store_w = [&](int bi) {
#pragma unroll
        for (int h = 0; h < 4; ++h) {
            int idx = h * 512 + tid;
            int r = idx >> 7, od = (idx & 127) * 2;
            *(double2*)(&Ws[bi][r][od]) = wreg[h];
        }
    };

    load_w(cbeg);
    mval = load_m(cbeg);
    store_w(0);
    __syncthreads();
    int cur = 0;
    for (int tile = 0; tile < NT; ++tile) {
        if (tile + 1 < NT) {
            int cn = cbeg + (tile + 1) * 16;
            load_w(cn);            // prefetch next tile into regs (covered by compute)
            mvaln = load_m(cn);
        }
#pragma unroll
        for (int k = 0; k < 16; ++k) {
            unsigned smk = (unsigned)__builtin_amdgcn_readlane((int)mval, k);
            unsigned soct = (smk >> w8s) & 0xffu;
            if (soct) {   // wave-uniform scalar branch
                double wf[4];
#pragma unroll
                for (int i2 = 0; i2 < 4; ++i2) wf[i2] = Ws[cur][k][lane + 64 * i2];
#pragma unroll
                for (int tj = 0; tj < 8; ++tj) {
                    if (soct & (1u << tj)) {
#pragma unroll
                        for (int i2 = 0; i2 < 4; ++i2) acc[tj][i2] += wf[i2];
                    }
                }
            }
        }
        if (tile + 1 < NT) {
            store_w(cur ^ 1);      // other buffer: prior reads of it ended before last barrier
            __syncthreads();       // ONE barrier per tile
        }
        mval = mvaln;
        cur ^= 1;
    }
#pragma unroll
    for (int tj = 0; tj < 8; ++tj) {
        int t = tb * 32 + w8s + tj;
        if (t < T_) {
            double* dst = Z + ((size_t)b * T_ + t) * O1_ + o0;
#pragma unroll
            for (int i2 = 0; i2 < 4; ++i2)
                dst[lane + 64 * i2] = acc[tj][i2];   // plain store (K-partial)
        }
    }
}

// ---------------- GEMM layer 2 DENSE f64 (branch-free FMA; s1 is too dense for masks) ----------------
// Evidence: rest-time ~455 us is robust while bottom-up accounting gives ~180;
// only gemm2s can hide under the 320-us top-5 cutoff.  Mechanism: LIF output
// density >> 10% -> octet gates never skip but still pay mask+branch per hit
// (r1's dense gemm2 config matched r4's sparse rest, so sparse never won).
// Dense inner loop: 8 LDS reads + 16 f64 FMA per k, zero branches.
// Tile 32m x 128o, 256 thr, grid (300, 4) = 1200 blocks (~4.7/CU).
// A staged as f32 (exact 0/1); products W*1.0 / W*0.0 exact in f64.
// Ascending c (tiles, then k) = r1's validated dense order -> exact.
// Full K in-block -> single Z output (scan#2 reads only zA).
__global__ __launch_bounds__(256, 4) void gemm2(const float* __restrict__ A,
                                                const double* __restrict__ Wt,
                                                double* __restrict__ Z) {
    __shared__ double Ws[16][128];   // 16 KB
    __shared__ float  As[32][20];    // 2.5 KB, padded
    int m0 = blockIdx.x * 32;
    int o0 = blockIdx.y * 128;
    int tid = threadIdx.x;
    int to = tid & 31, tm = tid >> 5;
    double acc[4][4];   // [i: o = o0+to+32i][j: m = m0+tm*4+j]
#pragma unroll
    for (int i = 0; i < 4; ++i)
#pragma unroll
        for (int j = 0; j < 4; ++j) acc[i][j] = 0.0;
    for (int c0 = 0; c0 < 512; c0 += 16) {
        {   // As: row = tid>>3 (0..31), pr = tid&7 -> 16 c's as float2
            int r = tid >> 3, pr = tid & 7;
            float2 v = *(const float2*)(A + (size_t)(m0 + r) * 512 + c0 + pr * 2);
            As[r][pr * 2 + 0] = v.x;
            As[r][pr * 2 + 1] = v.y;
        }
#pragma unroll
        for (int h = 0; h < 4; ++h) {   // Ws: 2048 doubles, linear double2
            int idx = h * 512 + tid * 2;
            int k = idx >> 7, o = idx & 127;
            *(double2*)(&Ws[k][o]) = *(const double2*)(Wt + (size_t)(c0 + k) * O2_ + o0 + o);
        }
        __syncthreads();
#pragma unroll
        for (int k = 0; k < 16; ++k) {
            double wf[4], xf[4];
#pragma unroll
            for (int i = 0; i < 4; ++i) wf[i] = Ws[k][to + 32 * i];
#pragma unroll
            for (int j = 0; j < 4; ++j) xf[j] = (double)As[tm * 4 + j][k];
#pragma unroll
            for (int i = 0; i < 4; ++i)
#pragma unroll
                for (int j = 0; j < 4; ++j) acc[i][j] = fma(wf[i], xf[j], acc[i][j]);
        }
        __syncthreads();
    }
#pragma unroll
    for (int j = 0; j < 4; ++j) {
        double* dst = Z + (size_t)(m0 + tm * 4 + j) * O2_ + o0;
#pragma unroll
        for (int i = 0; i < 4; ++i) dst[to + 32 * i] = acc[i][j];
    }
}

// ---------------- GEMM layer 3 (f64 acc) ----------------
__global__ void gemm3(const float* __restrict__ A,
                      const double* __restrict__ Wt,
                      double* __restrict__ Z) {
    __shared__ double w[512 * 16];
    for (int e = threadIdx.x; e < 4096; e += 256)
        ((double2*)w)[e] = ((const double2*)Wt)[e];
    __syncthreads();
    int m = blockIdx.x * 256 + threadIdx.x;
    if (m >= M_) return;
    double acc[O3_];
#pragma unroll
    for (int o = 0; o < O3_; ++o) acc[o] = 0.0;
    const float4* Ar = (const float4*)(A + (size_t)m * 512);
    for (int cq = 0; cq < 128; ++cq) {
        float4 a = Ar[cq];
        float av[4] = {a.x, a.y, a.z, a.w};
#pragma unroll
        for (int u = 0; u < 4; ++u)
#pragma unroll
            for (int o = 0; o < O3_; ++o) acc[o] += (double)av[u] * w[(cq * 4 + u) * 16 + o];
    }
    double* dst = Z + (size_t)m * 16;
#pragma unroll
    for (int o = 0; o < O3_; ++o) dst[o] = acc[o];
}

// ---------------- LIF scan + delay, layers 1/2 (O=512, f64 state) ----------------
__global__ void scan12(const double* __restrict__ Za,   // [B, T, 512] f64
                       const double* __restrict__ Zb,   // partial 2 or nullptr
                       const int* __restrict__ delay,   // [512]
                       float* __restrict__ Sout,        // [B, T, 512] f32 or nullptr
                       unsigned* __restrict__ bitsOut,  // [B, 512, 10] u32 or nullptr
                       float* __restrict__ sumOut) {
    int blk = blockIdx.x;
    int o = (blk & 7) * 64 + threadIdx.x;
    int b = blk >> 3;
    size_t base = (size_t)b * T_ * O1_ + o;
    const double* z  = Za + base;
    const double* z2 = Zb ? Zb + base : nullptr;
    float* s = Sout ? Sout + base : nullptr;
    int d = delay[o];
    if (s) for (int t = 0; t < d; ++t) s[(size_t)t * O1_] = 0.f;
    double cur = 0.0, vol = 0.0;
    float cnt = 0.f;
    unsigned bw = 0u;   // running bit word; d<32 so words 0..8 flush in-loop
    for (int t8 = 0; t8 < 296; t8 += 8) {
        double zbuf[8];
#pragma unroll
        for (int u = 0; u < 8; ++u) zbuf[u] = z[(size_t)(t8 + u) * O1_];
        if (z2) {
#pragma unroll
            for (int u = 0; u < 8; ++u) zbuf[u] += z2[(size_t)(t8 + u) * O1_];
        }
#pragma unroll
        for (int u = 0; u < 8; ++u) {
            int t = t8 + u;
            cur = cur * 0.75 + zbuf[u];
            vol = vol * 0.97 + cur;
            float sp = (vol >= 1.25) ? 1.f : 0.f;
            if (sp > 0.f) vol = 0.0;
            int tw = t + d;
            if (tw < T_) {
                if (s) s[(size_t)tw * O1_] = sp;
                cnt += sp;
                if (bitsOut) {
                    if (sp > 0.f) bw |= 1u << (tw & 31);
                    if ((tw & 31) == 31) { bitsOut[((size_t)b * O1_ + o) * 10 + (tw >> 5)] = bw; bw = 0u; }
                }
            }
        }
    }
    {
        double zbuf[4];
#pragma unroll
        for (int u = 0; u < 4; ++u) zbuf[u] = z[(size_t)(296 + u) * O1_];
        if (z2) {
#pragma unroll
            for (int u = 0; u < 4; ++u) zbuf[u] += z2[(size_t)(296 + u) * O1_];
        }
#pragma unroll
        for (int u = 0; u < 4; ++u) {
            int t = 296 + u;
            cur = cur * 0.75 + zbuf[u];
            vol = vol * 0.97 + cur;
            float sp = (vol >= 1.25) ? 1.f : 0.f;
            if (sp > 0.f) vol = 0.0;
            int tw = t + d;
            if (tw < T_) {
                if (s) s[(size_t)tw * O1_] = sp;
                cnt += sp;
                if (bitsOut) {
                    if (sp > 0.f) bw |= 1u << (tw & 31);
                    if ((tw & 31) == 31) { bitsOut[((size_t)b * O1_ + o) * 10 + (tw >> 5)] = bw; bw = 0u; }
                }
            }
        }
    }
    if (bitsOut) bitsOut[((size_t)b * O1_ + o) * 10 + 9] = bw;  // word 9 never flushes in-loop
    for (int off = 32; off; off >>= 1) cnt += __shfl_down(cnt, off);
    if (threadIdx.x == 0) atomicAdd(sumOut, cnt);
}

// ---------------- LIF scan + delay, layer 3 (O=10, f64 state) ----------------
__global__ void scan3(const double* __restrict__ Z3,  // [M, 16] f64
                      const int* __restrict__ d3,     // [10]
                      float* __restrict__ out,        // d_out: [B, 10, 300] f32
                      float* __restrict__ sumOut) {
    __shared__ double zt[T_ * 16];
    int b = blockIdx.x;
    const double2* src = (const double2*)(Z3 + (size_t)b * T_ * 16);
    for (int e = threadIdx.x; e < T_ * 8; e += 64)
        ((double2*)zt)[e] = src[e];
    __syncthreads();
    int o = threadIdx.x;
    if (o < O3_) {
        int d = d3[o];
        float* dst = out + (size_t)b * O3_ * T_ + (size_t)o * T_;
        for (int t = 0; t < d; ++t) dst[t] = 0.f;
        double cur = 0.0, vol = 0.0;
        float cnt = 0.f;
        for (int t = 0; t < T_; ++t) {
            cur = cur * 0.75 + zt[t * 16 + o];
            vol = vol * 0.97 + cur;
            float sp = (vol >= 1.25) ? 1.f : 0.f;
            if (sp > 0.f) vol = 0.0;
            int tw = t + d;
            if (tw < T_) { dst[tw] = sp; cnt += sp; }
        }
        atomicAdd(sumOut, cnt);
    }
}

__global__ void finalize(const float* __restrict__ sums, float* __restrict__ out) {
    if (threadIdx.x == 0) {
        out[0] = (float)((double)sums[0] / (double)(B_ * O1_ * T_));
        out[1] = (float)((double)sums[1] / (double)(B_ * O2_ * T_));
        out[2] = (float)((double)sums[2] / (double)(B_ * O3_ * T_));
    }
}

extern "C" void kernel_launch(void* const* d_in, const int* in_sizes, int n_in,
                              void* d_out, int out_size, void* d_ws, size_t ws_size,
                              hipStream_t stream) {
    const float* spike = (const float*)d_in[0];
    const float* v1 = (const float*)d_in[1];
    const float* g1 = (const float*)d_in[2];
    const float* v2 = (const float*)d_in[3];
    const float* g2 = (const float*)d_in[4];
    const float* v3 = (const float*)d_in[5];
    const float* g3 = (const float*)d_in[6];
    const int* d1 = (const int*)d_in[7];
    const int* d2 = (const int*)d_in[8];
    const int* d3 = (const int*)d_in[9];
    float* out = (float*)d_out;

    // Workspace: ~115 MB (round-4 layout).
    double* dw = (double*)d_ws;
    size_t off = 0;
    double* f1  = dw + off; off += 512;
    double* f2  = dw + off; off += 512;
    double* f3  = dw + off; off += 16;
    double* Wt1 = dw + off; off += (size_t)C1_ * O1_;
    double* Wt2 = dw + off; off += 512 * 512;
    double* Wt3 = dw + off; off += 512 * 16;
    double* zA  = dw + off; off += (size_t)M_ * 512;
    double* zB  = dw + off; off += (size_t)M_ * 512;
    double* z3b = dw + off; off += (size_t)M_ * 16;
    float* fw = (float*)(dw + off);
    float* sB    = fw;                                   // f32 spikes, M*512
    float* sums  = fw + (size_t)M_ * 512;                // 4 floats
    unsigned* Xbits = (unsigned*)(fw + (size_t)M_ * 512 + 4);  // B*C1*10 u32
    (void)ws_size; (void)out_size; (void)in_sizes; (void)n_in;

    hipMemsetAsync(sums, 0, 4 * sizeof(float), stream);

    build_bits<<<(B_ * C1_ * 10 + 255) / 256, 256, 0, stream>>>(spike, Xbits);

    calc_f<<<512, 256, 0, stream>>>(v1, g1, f1, O1_, C1_);
    calc_f<<<512, 256, 0, stream>>>(v2, g2, f2, O2_, O1_);
    calc_f<<<O3_, 256, 0, stream>>>(v3, g3, f3, O3_, O2_);

    transpose_scale<<<dim3((C1_ + 31) / 32, 16), dim3(32, 8), 0, stream>>>(v1, f1, Wt1, O1_, C1_, O1_);
    transpose_scale<<<dim3(16, 16), dim3(32, 8), 0, stream>>>(v2, f2, Wt2, O2_, O1_, O2_);
    transpose_scale<<<dim3(16, 1), dim3(32, 8), 0, stream>>>(v3, f3, Wt3, O3_, O2_, 16);

    // gemm1 (round-4, 320 us): 640 blocks x 512 thr, dbuf 1-barrier, K=2 plain partials
    gemm1<<<640, 512, 0, stream>>>(Xbits, Wt1, zA, zB);
    // scan12 #1: sum zA+zB, emit s1 FLOATS (dense gemm2 consumes floats; no bits)
    scan12<<<256, 64, 0, stream>>>(zA, zB, d1, sB, nullptr, sums + 0);
    // gemm2 DENSE f64: 1200 blocks x 256 thr, full K, single zA output
    gemm2<<<dim3(300, 4), 256, 0, stream>>>(sB, Wt2, zA);
    // scan12 #2: zA only, emit s2 floats
    scan12<<<256, 64, 0, stream>>>(zA, nullptr, d2, sB, nullptr, sums + 1);
    gemm3<<<(M_ + 255) / 256, 256, 0, stream>>>(sB, Wt3, z3b);        // z3b = z3
    scan3<<<B_, 64, 0, stream>>>(z3b, d3, out, sums + 2);
    finalize<<<1, 64, 0, stream>>>(sums, out + (size_t)B_ * O3_ * T_);
}